// Round 6
// baseline (209.586 us; speedup 1.0000x reference)
//
#include <hip/hip_runtime.h>
#include <hip/hip_bf16.h>
#include <stdint.h>

namespace {

constexpr int IDIM   = 512;
constexpr int ODIM   = 512;
constexpr int KTOT   = 32768;            // 2 * IDIM * 32
constexpr int BM = 128, BN = 128, BK = 64;
constexpr int SPLITK = 8;
constexpr int KCHUNK = KTOT / SPLITK;    // 4096
constexpr int NSTEP  = KCHUNK / BK;      // 64

typedef short    bf16x8 __attribute__((ext_vector_type(8)));
typedef float    f32x4  __attribute__((ext_vector_type(4)));
typedef float    f32x2  __attribute__((ext_vector_type(2)));
typedef uint32_t u32x4  __attribute__((ext_vector_type(4)));

__device__ __forceinline__ uint32_t f2bf1(float f) {
  union { float f; uint32_t u; } v; v.f = f;
  return (v.u + 0x7fffu + ((v.u >> 16) & 1u)) >> 16;   // RTNE
}
__device__ __forceinline__ uint32_t pk2(float lo, float hi) {
  return f2bf1(lo) | (f2bf1(hi) << 16);
}

// async global->LDS, 16B per lane; lds dest must be wave-uniform (HW adds lane*16)
__device__ __forceinline__ void gload_lds16(const void* gsrc, const char* ldsdst) {
  __builtin_amdgcn_global_load_lds(
      (const __attribute__((address_space(1))) uint32_t*)(uintptr_t)gsrc,
      (__attribute__((address_space(3))) uint32_t*)(uint32_t)(uintptr_t)ldsdst,
      16, 0, 0);
}

// ---------------- register-transpose convert: fc f32 [32768][512] -> wt bf16 [512][32768]
// Per wave: lane l covers o = o0 + l*2 (+0,+1); 32 k-iterations, float2 coalesced reads
// (512B/wave-instr); pack in regs; write 2 rows x 64B aligned runs. No LDS, no barrier.
__global__ __launch_bounds__(256) void transpose_convert_kernel(const float* __restrict__ fc,
                                                                uint16_t* __restrict__ wt) {
  const int t = threadIdx.x, lane = t & 63, wave = t >> 6;
  const int bid = blockIdx.x;
  const int ot = bid & 3;                  // 4 o-tiles of 128
  const int kt = bid >> 2;                 // 256 k-tiles of 128
  const int o0 = ot * 128 + lane * 2;
  const int kb = kt * 128 + wave * 32;     // wave covers 32 k
  const float* src = fc + (size_t)kb * ODIM + o0;
  uint32_t w0[16], w1[16];
#pragma unroll
  for (int p = 0; p < 16; ++p) {
    f32x2 a = *(const f32x2*)(src + (size_t)(2 * p) * ODIM);
    f32x2 b = *(const f32x2*)(src + (size_t)(2 * p + 1) * ODIM);
    w0[p] = pk2(a.x, b.x);                 // row o0:   k=kb+2p (lo), kb+2p+1 (hi)
    w1[p] = pk2(a.y, b.y);                 // row o0+1
  }
  uint16_t* dst0 = wt + (size_t)o0 * KTOT + kb;
  uint16_t* dst1 = dst0 + KTOT;
#pragma unroll
  for (int c = 0; c < 4; ++c) {
    *(u32x4*)(dst0 + c * 8) = *(const u32x4*)&w0[c * 4];
    *(u32x4*)(dst1 + c * 8) = *(const u32x4*)&w1[c * 4];
  }
}

// ---------------- out[b][o] = bias[o]
__global__ __launch_bounds__(256) void init_bias_kernel(const float* __restrict__ bias,
                                                        float* __restrict__ out) {
  int i = blockIdx.x * 256 + threadIdx.x;        // 262144 float4 slots
  ((f32x4*)out)[i] = ((const f32x4*)bias)[i & 127];
}

// ---------------- fused trig-feature GEMM, split-K with atomic reduce
// (verbatim round-1 verified version: 108 us, absmax 0.031)
__global__ __launch_bounds__(256, 2) void fkan_gemm_kernel(const float* __restrict__ x,
                                                           const uint16_t* __restrict__ wt,
                                                           float* __restrict__ out) {
  __shared__ char lds[65536];   // A dbuf: [0,32K)  W dbuf: [32K,64K), 16KB each

  const int t    = threadIdx.x;
  const int lane = t & 63;
  const int wave = t >> 6;

  // XCD-aware swizzle (512 % 8 == 0 -> bijective)
  int bid = blockIdx.x;
  int swz = (bid & 7) * 64 + (bid >> 3);
  const int bm = swz & 15;          // 16 M-blocks
  const int bn = (swz >> 4) & 3;    // 4  N-blocks
  const int bz = swz >> 6;          // 8  K-chunks

  const int row0  = bm * BM;
  const int col0  = bn * BN;
  const int kc0   = bz * KCHUNK;
  const int sflag = bz >> 2;              // 0: cos half, 1: sin half
  const int ibase = (bz & 3) * 128;       // 128 i-values per chunk

  // ---- A generation mapping: thread -> (row gr, i-offset ioff)
  const int gr   = t & 127;
  const int ioff = t >> 7;
  const float* xp = x + (size_t)(row0 + gr) * IDIM + ibase + ioff;
  int awoff[4];                           // swizzled ds_write_b128 offsets
#pragma unroll
  for (int j = 0; j < 4; ++j)
    awoff[j] = gr * 128 + (((ioff * 4 + j) ^ (gr & 7)) << 4);

  // ---- W staging: 4 rounds x (256 threads * 16B) = 16KB/step, source pre-swizzled
  const uint16_t* wsrc[4];
  int wdst[4];
#pragma unroll
  for (int q = 0; q < 4; ++q) {
    int nl   = q * 32 + wave * 8 + (lane >> 3);
    int slot = lane & 7;
    wsrc[q] = wt + (size_t)(col0 + nl) * KTOT + kc0 + ((slot ^ (nl & 7)) << 3);
    wdst[q] = q * 4096 + wave * 1024;     // wave-uniform; HW adds lane*16
  }

  // ---- fragment read offsets (swizzled)
  const int wm = wave >> 1, wn = wave & 1;
  int arow[4], ar7[4], bcol[4], bc7[4];
#pragma unroll
  for (int m = 0; m < 4; ++m) {
    int rr = wm * 64 + m * 16 + (lane & 15);
    arow[m] = rr * 128; ar7[m] = rr & 7;
    int cc = wn * 64 + m * 16 + (lane & 15);
    bcol[m] = cc * 128; bc7[m] = cc & 7;
  }

  f32x4 acc[4][4] = {};

  auto stageW = [&](int buf, int st) {
#pragma unroll
    for (int q = 0; q < 4; ++q)
      gload_lds16(wsrc[q] + st * BK, lds + 32768 + buf * 16384 + wdst[q]);
  };

  auto genA = [&](int buf, float ang) {
    float sv, cv;
    __sincosf(ang, &sv, &cv);
    const float c2 = 2.f * cv;
    float pm1 = sflag ? 0.f : 1.f;        // g=0 value
    float p   = sflag ? sv  : cv;         // g=1 value
    char* ab = lds + buf * 16384;
#pragma unroll
    for (int grp = 0; grp < 4; ++grp) {
      u32x4 w;
#pragma unroll
      for (int u = 0; u < 4; ++u) {
        float a0 = p; float nx = c2 * p - pm1; pm1 = p; p = nx;
        float a1 = p; nx = c2 * p - pm1; pm1 = p; p = nx;
        w[u] = pk2(a0, a1);
      }
      *(u32x4*)(ab + awoff[grp]) = w;
    }
  };

  auto compute = [&](int buf) {
    const char* ab = lds + buf * 16384;
    const char* wb = lds + 32768 + buf * 16384;
#pragma unroll
    for (int ks = 0; ks < 2; ++ks) {
      const int ksb = ks * 4 + (lane >> 4);
      bf16x8 af[4], bfr[4];
#pragma unroll
      for (int m = 0; m < 4; ++m)
        af[m] = *(const bf16x8*)(ab + arow[m] + ((ksb ^ ar7[m]) << 4));
#pragma unroll
      for (int n = 0; n < 4; ++n)
        bfr[n] = *(const bf16x8*)(wb + bcol[n] + ((ksb ^ bc7[n]) << 4));
#pragma unroll
      for (int m = 0; m < 4; ++m)
#pragma unroll
        for (int n = 0; n < 4; ++n)
          acc[m][n] = __builtin_amdgcn_mfma_f32_16x16x32_bf16(af[m], bfr[n], acc[m][n], 0, 0, 0);
    }
  };

  // prologue: stage step 0
  float ang0 = xp[0];
  stageW(0, 0);
  genA(0, ang0);
  float angN = xp[2];                      // angle for step 1
  __syncthreads();

  int cur = 0;
  for (int st = 0; st < NSTEP; ++st) {
    if (st + 1 < NSTEP) {
      float aU = angN;
      int pf = (st + 2 < NSTEP) ? (st + 2) : (NSTEP - 1);
      angN = xp[2 * pf];                   // prefetch one step ahead
      stageW(cur ^ 1, st + 1);
      genA(cur ^ 1, aU);
    }
    compute(cur);
    __syncthreads();                       // drains vmcnt+lgkmcnt
    cur ^= 1;
  }

  // epilogue: split-K reduce via atomics (out pre-initialized with bias)
#pragma unroll
  for (int m = 0; m < 4; ++m) {
#pragma unroll
    for (int n = 0; n < 4; ++n) {
      int rr = row0 + wm * 64 + m * 16 + ((lane >> 4) << 2);
      int cc = col0 + wn * 64 + n * 16 + (lane & 15);
#pragma unroll
      for (int j = 0; j < 4; ++j)
        atomicAdd(out + (size_t)(rr + j) * ODIM + cc, acc[m][n][j]);
    }
  }
}

}  // namespace

extern "C" void kernel_launch(void* const* d_in, const int* in_sizes, int n_in,
                              void* d_out, int out_size, void* d_ws, size_t ws_size,
                              hipStream_t stream) {
  const float* x    = (const float*)d_in[0];
  const float* fc   = (const float*)d_in[1];   // [2,512,32,512] == [32768][512]
  const float* bias = (const float*)d_in[2];
  float*    out = (float*)d_out;
  uint16_t* wt  = (uint16_t*)d_ws;             // 512*32768*2 = 33.5 MB, o-major

  transpose_convert_kernel<<<1024, 256, 0, stream>>>(fc, wt);
  init_bias_kernel<<<1024, 256, 0, stream>>>(bias, out);
  fkan_gemm_kernel<<<512, 256, 0, stream>>>(x, wt, out);
}

// Round 7
// 198.674 us; speedup vs baseline: 1.0549x; 1.0549x over previous
//
#include <hip/hip_runtime.h>
#include <hip/hip_bf16.h>
#include <stdint.h>

namespace {

constexpr int IDIM   = 512;
constexpr int ODIM   = 512;
constexpr int KTOT   = 32768;            // 2 * IDIM * 32
constexpr int BM = 128, BN = 128, BK = 64;
constexpr int SPLITK = 8;
constexpr int KCHUNK = KTOT / SPLITK;    // 4096
constexpr int NSTEP  = KCHUNK / BK;      // 64

typedef short    bf16x8 __attribute__((ext_vector_type(8)));
typedef float    f32x4  __attribute__((ext_vector_type(4)));
typedef float    f32x2  __attribute__((ext_vector_type(2)));
typedef uint32_t u32x4  __attribute__((ext_vector_type(4)));

__device__ __forceinline__ uint32_t f2bf1(float f) {
  union { float f; uint32_t u; } v; v.f = f;
  return (v.u + 0x7fffu + ((v.u >> 16) & 1u)) >> 16;   // RTNE
}
__device__ __forceinline__ uint32_t pk2(float lo, float hi) {
  return f2bf1(lo) | (f2bf1(hi) << 16);
}

// fast pack: round-half-up (+0x8000) then v_perm_b32 grabs the two high halves.
// 3 VALU ops vs 9 for RTNE; |err| <= 0.5 ulp bf16.
__device__ __forceinline__ uint32_t pk2f(float lo, float hi) {
  union { float f; uint32_t u; } a, b; a.f = lo; b.f = hi;
  return __builtin_amdgcn_perm(b.u + 0x8000u, a.u + 0x8000u, 0x07060302u);
}

// async global->LDS, 16B per lane; lds dest must be wave-uniform (HW adds lane*16)
__device__ __forceinline__ void gload_lds16(const void* gsrc, const char* ldsdst) {
  __builtin_amdgcn_global_load_lds(
      (const __attribute__((address_space(1))) uint32_t*)(uintptr_t)gsrc,
      (__attribute__((address_space(3))) uint32_t*)(uint32_t)(uintptr_t)ldsdst,
      16, 0, 0);
}

#define WAIT_LGKM0   asm volatile("s_waitcnt lgkmcnt(0)" ::: "memory")
#define WAIT_VM(N)   asm volatile("s_waitcnt vmcnt(" #N ")" ::: "memory")
#define FENCE        asm volatile("" ::: "memory")

// ---------------- register-transpose convert: fc f32 [32768][512] -> wt bf16 [512][32768]
__global__ __launch_bounds__(256) void transpose_convert_kernel(const float* __restrict__ fc,
                                                                uint16_t* __restrict__ wt) {
  const int t = threadIdx.x, lane = t & 63, wave = t >> 6;
  const int bid = blockIdx.x;
  const int ot = bid & 3;                  // 4 o-tiles of 128
  const int kt = bid >> 2;                 // 256 k-tiles of 128
  const int o0 = ot * 128 + lane * 2;
  const int kb = kt * 128 + wave * 32;     // wave covers 32 k
  const float* src = fc + (size_t)kb * ODIM + o0;
  uint32_t w0[16], w1[16];
#pragma unroll
  for (int p = 0; p < 16; ++p) {
    f32x2 a = *(const f32x2*)(src + (size_t)(2 * p) * ODIM);
    f32x2 b = *(const f32x2*)(src + (size_t)(2 * p + 1) * ODIM);
    w0[p] = pk2(a.x, b.x);                 // row o0:   k=kb+2p (lo), kb+2p+1 (hi)
    w1[p] = pk2(a.y, b.y);                 // row o0+1
  }
  uint16_t* dst0 = wt + (size_t)o0 * KTOT + kb;
  uint16_t* dst1 = dst0 + KTOT;
#pragma unroll
  for (int c = 0; c < 4; ++c) {
    *(u32x4*)(dst0 + c * 8) = *(const u32x4*)&w0[c * 4];
    *(u32x4*)(dst1 + c * 8) = *(const u32x4*)&w1[c * 4];
  }
}

// ---------------- out[b][o] = bias[o]
__global__ __launch_bounds__(256) void init_bias_kernel(const float* __restrict__ bias,
                                                        float* __restrict__ out) {
  int i = blockIdx.x * 256 + threadIdx.x;        // 262144 float4 slots
  ((f32x4*)out)[i] = ((const f32x4*)bias)[i & 127];
}

// ---------------- fused trig-feature GEMM, split-K, 3-buf counted-vmcnt pipeline
__global__ __launch_bounds__(256, 2) void fkan_gemm_kernel(const float* __restrict__ x,
                                                           const uint16_t* __restrict__ wt,
                                                           float* __restrict__ out) {
  __shared__ char lds[81920];   // A dbuf [0,32K); W 3-buf [32K,80K), 16KB each

  const int t    = threadIdx.x;
  const int lane = t & 63;
  const int wave = t >> 6;

  // XCD-aware swizzle (512 % 8 == 0 -> bijective)
  int bid = blockIdx.x;
  int swz = (bid & 7) * 64 + (bid >> 3);
  const int bm = swz & 15;          // 16 M-blocks
  const int bn = (swz >> 4) & 3;    // 4  N-blocks
  const int bz = swz >> 6;          // 8  K-chunks

  const int row0  = bm * BM;
  const int col0  = bn * BN;
  const int kc0   = bz * KCHUNK;
  const int sflag = bz >> 2;              // 0: cos half, 1: sin half
  const int ibase = (bz & 3) * 128;       // 128 i-values per chunk

  // ---- A generation mapping: thread -> (row gr, i-offset ioff)
  const int gr   = t & 127;
  const int ioff = t >> 7;
  const float* xp = x + (size_t)(row0 + gr) * IDIM + ibase + ioff;
  int awoff[4];                           // swizzled ds_write_b128 offsets
#pragma unroll
  for (int j = 0; j < 4; ++j)
    awoff[j] = gr * 128 + (((ioff * 4 + j) ^ (gr & 7)) << 4);

  // ---- W staging: 4 x (256 threads * 16B) = 16KB/step, source pre-swizzled.
  // Pointers advance by BK per staged step (no per-step 64b re-addressing).
  const uint16_t* wptr[4];
  int wdst[4];
#pragma unroll
  for (int q = 0; q < 4; ++q) {
    int nl   = q * 32 + wave * 8 + (lane >> 3);
    int slot = lane & 7;
    wptr[q] = wt + (size_t)(col0 + nl) * KTOT + kc0 + ((slot ^ (nl & 7)) << 3);
    wdst[q] = q * 4096 + wave * 1024;     // wave-uniform; HW adds lane*16
  }

  // ---- fragment read offsets (swizzled) — verified round-1 path
  const int wm = wave >> 1, wn = wave & 1;
  int arow[4], ar7[4], bcol[4], bc7[4];
#pragma unroll
  for (int m = 0; m < 4; ++m) {
    int rr = wm * 64 + m * 16 + (lane & 15);
    arow[m] = rr * 128; ar7[m] = rr & 7;
    int cc = wn * 64 + m * 16 + (lane & 15);
    bcol[m] = cc * 128; bc7[m] = cc & 7;
  }

  f32x4 acc[4][4] = {};

  auto stageW = [&](int buf) {            // stages next unstaged step, advances wptr
#pragma unroll
    for (int q = 0; q < 4; ++q) {
      gload_lds16(wptr[q], lds + 32768 + buf * 16384 + wdst[q]);
      wptr[q] += BK;
    }
  };

  // genA: two independent stride-2 Chebyshev chains (odd/even g) via cos/sin 2x.
  // Emits g = 1..32 in order, packed in pairs.
  auto genA = [&](int abuf, float ang) {
    float s1, c1;
    __sincosf(ang, &s1, &c1);
    const float c2 = 2.f * c1 * c1 - 1.f;   // cos 2x
    const float s2 = 2.f * s1 * c1;         // sin 2x
    const float k2 = 2.f * c2;
    float po  = sflag ? s1   : c1;          // g = 1
    float pe  = sflag ? s2   : c2;          // g = 2
    float pom = sflag ? -s1  : c1;          // g = -1
    float pem = sflag ? 0.f  : 1.f;         // g = 0
    char* ab = lds + abuf * 16384;
#pragma unroll
    for (int grp = 0; grp < 4; ++grp) {
      u32x4 w;
#pragma unroll
      for (int u = 0; u < 4; ++u) {
        w[u] = pk2f(po, pe);
        float no = k2 * po - pom; pom = po; po = no;
        float ne = k2 * pe - pem; pem = pe; pe = ne;
      }
      *(u32x4*)(ab + awoff[grp]) = w;
    }
  };

  auto compute = [&](int wbuf, int abuf) { // verified round-1 fragment path
    const char* ab = lds + abuf * 16384;
    const char* wb = lds + 32768 + wbuf * 16384;
#pragma unroll
    for (int ks = 0; ks < 2; ++ks) {
      const int ksb = ks * 4 + (lane >> 4);
      bf16x8 af[4], bfr[4];
#pragma unroll
      for (int m = 0; m < 4; ++m)
        af[m] = *(const bf16x8*)(ab + arow[m] + ((ksb ^ ar7[m]) << 4));
#pragma unroll
      for (int n = 0; n < 4; ++n)
        bfr[n] = *(const bf16x8*)(wb + bcol[n] + ((ksb ^ bc7[n]) << 4));
#pragma unroll
      for (int m = 0; m < 4; ++m)
#pragma unroll
        for (int n = 0; n < 4; ++n)
          acc[m][n] = __builtin_amdgcn_mfma_f32_16x16x32_bf16(af[m], bfr[n], acc[m][n], 0, 0, 0);
    }
  };

  // ---- prologue: stage steps 0,1; gen A(0)
  float angCur  = xp[0];
  float angNext = xp[2];
  stageW(0);                 // step 0 -> wbuf 0
  stageW(1);                 // step 1 -> wbuf 1
  genA(0, angCur);
  WAIT_VM(4);                // step-0 W landed (step-1's 4 may be in flight)
  WAIT_LGKM0;                // own A writes drained
  __builtin_amdgcn_s_barrier();
  FENCE;

  int wb_c = 0;              // compute W buf
  int ws_c = 2;              // next stage W buf
  for (int st = 0; st < NSTEP; ++st) {
    const int ab = st & 1;
    if (st + 2 < NSTEP) {
      stageW(ws_c);
      ws_c = (ws_c == 2) ? 0 : ws_c + 1;
    }
    if (st + 1 < NSTEP) {
      float a = angNext;
      if (st + 2 < NSTEP) angNext = xp[2 * (st + 2)];
      genA(ab ^ 1, a);
    }
    compute(wb_c, ab);
    wb_c = (wb_c == 2) ? 0 : wb_c + 1;
    if (st + 1 < NSTEP) {
      WAIT_LGKM0;            // A-writes visible to other waves past the barrier
      if (st + 2 < NSTEP) { WAIT_VM(4); } else { WAIT_VM(0); }
      __builtin_amdgcn_s_barrier();
      FENCE;
    }
  }

  // ---- epilogue: split-K reduce via atomics (out pre-initialized with bias)
#pragma unroll
  for (int m = 0; m < 4; ++m) {
#pragma unroll
    for (int n = 0; n < 4; ++n) {
      int rr = row0 + wm * 64 + m * 16 + ((lane >> 4) << 2);
      int cc = col0 + wn * 64 + n * 16 + (lane & 15);
#pragma unroll
      for (int j = 0; j < 4; ++j)
        atomicAdd(out + (size_t)(rr + j) * ODIM + cc, acc[m][n][j]);
    }
  }
}

}  // namespace

extern "C" void kernel_launch(void* const* d_in, const int* in_sizes, int n_in,
                              void* d_out, int out_size, void* d_ws, size_t ws_size,
                              hipStream_t stream) {
  const float* x    = (const float*)d_in[0];
  const float* fc   = (const float*)d_in[1];   // [2,512,32,512] == [32768][512]
  const float* bias = (const float*)d_in[2];
  float*    out = (float*)d_out;
  uint16_t* wt  = (uint16_t*)d_ws;             // 512*32768*2 = 33.5 MB, o-major

  transpose_convert_kernel<<<1024, 256, 0, stream>>>(fc, wt);
  init_bias_kernel<<<1024, 256, 0, stream>>>(bias, out);
  fkan_gemm_kernel<<<512, 256, 0, stream>>>(x, wt, out);
}